// Round 12
// baseline (173.686 us; speedup 1.0000x reference)
//
#include <hip/hip_runtime.h>

// SelfAttention: B=4, S=2048, D=1024, fp32 in/out. bf16 MFMA, fp32 accum.
// R11: 32x32x16 MFMA (2x FLOP/inst) in the validated core2 skeleton.
// Unified R1-R10 finding: time ~ MFMA instruction count (~13cyc/inst issue tax,
// schedule/occupancy/phase variants all null) -> halve instructions at const FLOPs.
//   qkproj: core2 GEOM0 256x256, grid (32,8) = 256 blocks (Q and K)
//   vproj:  core2 GEOM1 128x256, grid (64,4) = 256 blocks (Vt transposed)
//   sc:     core2 GEOM0, grid (8,8,4) = 256, P~=exp(QK^T/32)+rowsums
//   pv:     core2 GEOM1, grid (16,4,4) = 256, * 1/rowsum (in-kernel rsum)
// Frag maps (m74/m101-verified): A/B lane&31=row|col, k=(lane>>5)*8+j;
// C/D col=lane&31, row=(reg&3)+8*(reg>>2)+4*(lane>>5).
// ws layout (MiB):
//   [0,16)   x_bf16 (proj) -> P~ bf16 [4][2048][2048]
//   [16,32)  Q bf16   [32,48) K bf16   [48,64) Vt bf16 [4][1024][2048]
//   [64,70)  Wq|Wk|Wv bf16
//   [70,+256K) rowpart fp32 [8][4][2048]

typedef __bf16 bf16x8 __attribute__((ext_vector_type(8)));
typedef float f32x16 __attribute__((ext_vector_type(16)));
typedef unsigned short u16;

__device__ __forceinline__ u16 f2b(float f) {
  union { float f; unsigned u; } a; a.f = f;
  unsigned r = a.u + 0x7fffu + ((a.u >> 16) & 1u);  // RNE
  return (u16)(r >> 16);
}

// blocks [0,8192): x (2097152 float4s). blocks [8192,11264): Wq|Wk|Wv.
__global__ __launch_bounds__(256) void cast_all_kernel(const float* __restrict__ x,
                                                       const float* __restrict__ Wq,
                                                       const float* __restrict__ Wk,
                                                       const float* __restrict__ Wv,
                                                       u16* __restrict__ xb,
                                                       u16* __restrict__ Wb) {
  int b = blockIdx.x;
  if (b < 8192) {
    const int i = b * 256 + threadIdx.x;
    float4 v = reinterpret_cast<const float4*>(x)[i];
    reinterpret_cast<ushort4*>(xb)[i] =
        make_ushort4(f2b(v.x), f2b(v.y), f2b(v.z), f2b(v.w));
  } else {
    b -= 8192;
    const int w = b >> 10;
    const float* src = (w == 0) ? Wq : (w == 1) ? Wk : Wv;
    const int i = (b & 1023) * 256 + threadIdx.x;
    float4 v = reinterpret_cast<const float4*>(src)[i];
    reinterpret_cast<ushort4*>(Wb + (size_t)w * 1048576)[i] =
        make_ushort4(f2b(v.x), f2b(v.y), f2b(v.z), f2b(v.w));
  }
}

// ---------------- merged-phase double-buffered core, 32x32x16 MFMA (R11) ----------------
// GEOM 0: BM=256,BN=256, acc f32x16[8] (4 mi x 2 ni); GEOM 1: BM=128,BN=256, acc f32x16[4].
// 8 waves: wr=wave>>2 (M), wc=wave&3 (N); wave tile GEOM0 128x64, GEOM1 64x64.
// BK=64 (2 halves x 2 ksteps of 16). Staging/swizzle/vmcnt/barriers = R7 core2, unchanged.
template <int GEOM, int NT>
__device__ __forceinline__ void core2(const char* __restrict__ Ab,
                                      const char* __restrict__ Bb, int lda, int ldb,
                                      char* smem, f32x16* acc) {
  constexpr int LDSBUF = GEOM ? 49152 : 65536;
  constexpr int BOFF = GEOM ? 16384 : 32768;
  constexpr int AHALF = GEOM ? 8192 : 16384;
  constexpr int NMI = GEOM ? 2 : 4;  // 32-row A subtiles per wave
  const int tid = threadIdx.x;
  const int wave = tid >> 6, lane = tid & 63;
  const int wr = wave >> 2, wc = wave & 3;
  const int hi16 = (lane >> 4) & 1;
  // pre-swizzled read base: row=lane&15 within 16-row subtile, k16-group=(lane>>5)
  const int rdbase = (((lane & 15) * 64 + (lane >> 5) * 16)) ^ (((lane >> 3) & 1) << 5);
  const int li = (lane * 16) ^ ((lane >> 5) << 5);
  const int sr = li >> 6, sc2 = li & 63;

  auto STAGE = [&](int kt, int s) {  // A-half s + B-half s of tile kt
    char* base = smem + (kt & 1) * LDSBUF;
    const int colOff = kt * 128 + s * 64 + sc2;
    char* ldsA = base + s * AHALF;
    __builtin_amdgcn_global_load_lds(
        (const __attribute__((address_space(1))) void*)(Ab + (size_t)(wave * 16 + sr) * lda + colOff),
        (__attribute__((address_space(3))) void*)(ldsA + wave * 1024), 16, 0, 0);
    if constexpr (GEOM == 0)
      __builtin_amdgcn_global_load_lds(
          (const __attribute__((address_space(1))) void*)(Ab + (size_t)((8 + wave) * 16 + sr) * lda + colOff),
          (__attribute__((address_space(3))) void*)(ldsA + 8192 + wave * 1024), 16, 0, 0);
    char* ldsB = base + BOFF + s * 16384;
    __builtin_amdgcn_global_load_lds(
        (const __attribute__((address_space(1))) void*)(Bb + (size_t)(wave * 16 + sr) * ldb + colOff),
        (__attribute__((address_space(3))) void*)(ldsB + wave * 1024), 16, 0, 0);
    __builtin_amdgcn_global_load_lds(
        (const __attribute__((address_space(1))) void*)(Bb + (size_t)((8 + wave) * 16 + sr) * ldb + colOff),
        (__attribute__((address_space(3))) void*)(ldsB + 8192 + wave * 1024), 16, 0, 0);
  };

  // prologue: both halves of tile 0; land half 0, keep half 1 in flight
  STAGE(0, 0);
  STAGE(0, 1);
  if constexpr (GEOM == 0) asm volatile("s_waitcnt vmcnt(4)" ::: "memory");
  else asm volatile("s_waitcnt vmcnt(3)" ::: "memory");
  __builtin_amdgcn_s_barrier();
  __builtin_amdgcn_sched_barrier(0);

  for (int kt = 0; kt < NT; ++kt) {
    const char* bufA = smem + (kt & 1) * LDSBUF;
    const char* bufB = bufA + BOFF;
#pragma unroll
    for (int s = 0; s < 2; ++s) {
      bf16x8 afr[2 * NMI], bfr[4];
#pragma unroll
      for (int ks = 0; ks < 2; ++ks) {
        const int inner = rdbase ^ (ks << 5);
#pragma unroll
        for (int mi = 0; mi < NMI; ++mi) {
          const int sub = wr * (GEOM ? 4 : 8) + mi * 2 + hi16;
          afr[ks * NMI + mi] =
              *reinterpret_cast<const bf16x8*>(bufA + s * AHALF + sub * 1024 + inner);
        }
#pragma unroll
        for (int ni = 0; ni < 2; ++ni) {
          const int sub = wc * 4 + ni * 2 + hi16;
          bfr[ks * 2 + ni] =
              *reinterpret_cast<const bf16x8*>(bufB + s * 16384 + sub * 1024 + inner);
        }
      }
      if (kt + 1 < NT) STAGE(kt + 1, s);
      __builtin_amdgcn_s_barrier();
      __builtin_amdgcn_sched_barrier(0);
      __builtin_amdgcn_s_setprio(1);
#pragma unroll
      for (int ks = 0; ks < 2; ++ks)
#pragma unroll
        for (int mi = 0; mi < NMI; ++mi)
#pragma unroll
          for (int ni = 0; ni < 2; ++ni)
            acc[mi * 2 + ni] = __builtin_amdgcn_mfma_f32_32x32x16_bf16(
                afr[ks * NMI + mi], bfr[ks * 2 + ni], acc[mi * 2 + ni], 0, 0, 0);
      __builtin_amdgcn_s_setprio(0);
      if (kt < NT - 1) {
        if constexpr (GEOM == 0) asm volatile("s_waitcnt vmcnt(4)" ::: "memory");
        else asm volatile("s_waitcnt vmcnt(3)" ::: "memory");
      } else if (s == 0) {
        asm volatile("s_waitcnt vmcnt(0)" ::: "memory");
      }
      __builtin_amdgcn_s_barrier();
      __builtin_amdgcn_sched_barrier(0);
    }
  }
}

// C/D row within a 32-row subtile
#define CROW(reg, hi) (((reg) & 3) + 8 * ((reg) >> 2) + 4 * (hi))

// ---------------- QK projection: GEOM0 256x256, grid (32,8) = 256 exact ----------------
__global__ __launch_bounds__(512, 2) void qkproj_kernel(
    const u16* __restrict__ A, const u16* __restrict__ Bm,
    const float* __restrict__ bq, const float* __restrict__ bk,
    u16* __restrict__ QK) {
  extern __shared__ char smem[];
  const int tileM = blockIdx.x * 256, tileN = blockIdx.y * 256;
  f32x16 acc[8] = {};
  core2<0, 16>((const char*)A + (size_t)tileM * 2048,
               (const char*)Bm + (size_t)tileN * 2048, 2048, 2048, smem, acc);
  const int tid = threadIdx.x;
  const int wave = tid >> 6, lane = tid & 63;
  const int wr = wave >> 2, wc = wave & 3, hi = lane >> 5, c31 = lane & 31;
  const int w = blockIdx.y >> 2;  // 0 -> Q, 1 -> K
  const float* bias = (w == 0) ? bq : bk;
  u16* O = QK + (size_t)w * 8388608;
#pragma unroll
  for (int mi = 0; mi < 4; ++mi) {
#pragma unroll
    for (int ni = 0; ni < 2; ++ni) {
      const int cw = (tileN + wc * 64 + ni * 32 + c31) & 1023;
      const float bi = bias[cw];
#pragma unroll
      for (int reg = 0; reg < 16; ++reg) {
        const int row = tileM + wr * 128 + mi * 32 + CROW(reg, hi);
        O[(size_t)row * 1024 + cw] = f2b(acc[mi * 2 + ni][reg] + bi);
      }
    }
  }
}

// ---------------- V projection: GEOM1 128x256, grid (64,4) = 256 exact ----------------
__global__ __launch_bounds__(512, 2) void vproj_kernel(
    const u16* __restrict__ A, const u16* __restrict__ Bv,
    const float* __restrict__ bvv, u16* __restrict__ Vt) {
  extern __shared__ char smem[];
  const int tileM = blockIdx.x * 128, tileN = blockIdx.y * 256;
  f32x16 acc[4] = {};
  core2<1, 16>((const char*)A + (size_t)tileM * 2048,
               (const char*)Bv + (size_t)tileN * 2048, 2048, 2048, smem, acc);
  const int tid = threadIdx.x;
  const int wave = tid >> 6, lane = tid & 63;
  const int wr = wave >> 2, wc = wave & 3, hi = lane >> 5, c31 = lane & 31;
#pragma unroll
  for (int mi = 0; mi < 2; ++mi) {
#pragma unroll
    for (int ni = 0; ni < 2; ++ni) {
      const int cw = (tileN + wc * 64 + ni * 32 + c31) & 1023;
      const float bi = bvv[cw];
#pragma unroll
      for (int q = 0; q < 4; ++q) {
        const int r0 = tileM + wr * 64 + mi * 32 + 8 * q + 4 * hi;  // rows r0..r0+3
        const int b = r0 >> 11, s0 = r0 & 2047;  // 4-aligned, never straddles batch
        ushort4 u = make_ushort4(
            f2b(acc[mi * 2 + ni][q * 4 + 0] + bi), f2b(acc[mi * 2 + ni][q * 4 + 1] + bi),
            f2b(acc[mi * 2 + ni][q * 4 + 2] + bi), f2b(acc[mi * 2 + ni][q * 4 + 3] + bi));
        *reinterpret_cast<ushort4*>(&Vt[(size_t)b * 2097152 + (size_t)cw * 2048 + s0]) = u;
      }
    }
  }
}

// ---------------- sc: P~ = exp(Q K^T / 32) (bf16) + row-sum partials ----------------
__global__ __launch_bounds__(512, 2) void sc8_kernel(const u16* __restrict__ Qb,
                                                     const u16* __restrict__ Kb,
                                                     u16* __restrict__ P,
                                                     float* __restrict__ rowpart) {
  extern __shared__ char smem[];
  const int z = blockIdx.z;
  const int tileM = blockIdx.x * 256, tileN = blockIdx.y * 256;
  f32x16 acc[8] = {};
  core2<0, 16>((const char*)Qb + (size_t)z * 4194304 + (size_t)tileM * 2048,
               (const char*)Kb + (size_t)z * 4194304 + (size_t)tileN * 2048, 2048, 2048,
               smem, acc);
  const int tid = threadIdx.x;
  const int wave = tid >> 6, lane = tid & 63;
  const int wr = wave >> 2, wc = wave & 3, hi = lane >> 5, c31 = lane & 31;
  float* rs = (float*)smem;  // [4][256]; safe: core2 ends with full barrier
  u16* Po = P + (size_t)z * 4194304 + (size_t)tileM * 2048 + tileN;
#pragma unroll
  for (int mi = 0; mi < 4; ++mi) {
#pragma unroll
    for (int reg = 0; reg < 16; ++reg) {
      const int rl = wr * 128 + mi * 32 + CROW(reg, hi);
      const float e0 = __expf(acc[mi * 2 + 0][reg] * 0.03125f);
      const float e1 = __expf(acc[mi * 2 + 1][reg] * 0.03125f);
      Po[(size_t)rl * 2048 + wc * 64 + c31] = f2b(e0);
      Po[(size_t)rl * 2048 + wc * 64 + 32 + c31] = f2b(e1);
      float part = e0 + e1;
      part += __shfl_xor(part, 1);
      part += __shfl_xor(part, 2);
      part += __shfl_xor(part, 4);
      part += __shfl_xor(part, 8);
      part += __shfl_xor(part, 16);
      if (c31 == 0) rs[wc * 256 + rl] = part;  // lanes 0 & 32: different rl
    }
  }
  __syncthreads();
  if (tid < 256) {
    float s = rs[tid] + rs[256 + tid] + rs[512 + tid] + rs[768 + tid];
    rowpart[(size_t)blockIdx.y * 8192 + z * 2048 + tileM + tid] = s;
  }
}

// ---------------- pv: out = (P~ Vt^T) * rowinv (rowinv computed in-kernel) ----------------
__global__ __launch_bounds__(512, 2) void pv8_kernel(const u16* __restrict__ P,
                                                     const u16* __restrict__ Vt,
                                                     const float* __restrict__ rowpart,
                                                     float* __restrict__ out) {
  extern __shared__ char smem[];  // 98304 core + 512 rowinv
  const int z = blockIdx.z;
  const int tileM = blockIdx.x * 128, tileN = blockIdx.y * 256;
  float* rinv = (float*)(smem + 98304);
  const int tid = threadIdx.x;
  if (tid < 128) {
    float s = 0.f;
#pragma unroll
    for (int t = 0; t < 8; ++t) s += rowpart[t * 8192 + z * 2048 + tileM + tid];
    rinv[tid] = 1.0f / s;
  }
  __builtin_amdgcn_sched_barrier(0);  // pin rinv writes before staging
  // core2's first barrier orders the rinv write before epilogue reads.
  f32x16 acc[4] = {};
  core2<1, 32>((const char*)P + (size_t)z * 8388608 + (size_t)tileM * 4096,
               (const char*)Vt + (size_t)z * 4194304 + (size_t)tileN * 4096, 4096, 4096,
               smem, acc);
  const int wave = tid >> 6, lane = tid & 63;
  const int wr = wave >> 2, wc = wave & 3, hi = lane >> 5, c31 = lane & 31;
  float* O = out + (size_t)z * 2097152;
#pragma unroll
  for (int mi = 0; mi < 2; ++mi) {
#pragma unroll
    for (int ni = 0; ni < 2; ++ni) {
#pragma unroll
      for (int reg = 0; reg < 16; ++reg) {
        const int r = wr * 64 + mi * 32 + CROW(reg, hi);
        O[(size_t)(tileM + r) * 1024 + tileN + wc * 64 + ni * 32 + c31] =
            acc[mi * 2 + ni][reg] * rinv[r];
      }
    }
  }
}

extern "C" void kernel_launch(void* const* d_in, const int* in_sizes, int n_in,
                              void* d_out, int out_size, void* d_ws, size_t ws_size,
                              hipStream_t stream) {
  if (ws_size < ((size_t)72 << 20)) return;
  const float* x = (const float*)d_in[0];
  const float* Wq = (const float*)d_in[1];
  const float* bq = (const float*)d_in[2];
  const float* Wk = (const float*)d_in[3];
  const float* bk = (const float*)d_in[4];
  const float* Wv = (const float*)d_in[5];
  const float* bv = (const float*)d_in[6];
  char* ws = (char*)d_ws;
  u16* xb = (u16*)(ws);                       // [0,16M); later P~ [4][2048][2048]
  u16* Pb = (u16*)(ws);
  u16* Qb = (u16*)(ws + ((size_t)16 << 20));
  u16* Kb = (u16*)(ws + ((size_t)32 << 20));
  u16* Vt = (u16*)(ws + ((size_t)48 << 20));
  u16* Wb = (u16*)(ws + ((size_t)64 << 20));
  float* rowpart = (float*)(ws + ((size_t)70 << 20));  // 256 KiB
  float* out = (float*)d_out;

  (void)hipFuncSetAttribute((const void*)qkproj_kernel,
                            hipFuncAttributeMaxDynamicSharedMemorySize, 131072);
  (void)hipFuncSetAttribute((const void*)vproj_kernel,
                            hipFuncAttributeMaxDynamicSharedMemorySize, 98304);
  (void)hipFuncSetAttribute((const void*)sc8_kernel,
                            hipFuncAttributeMaxDynamicSharedMemorySize, 131072);
  (void)hipFuncSetAttribute((const void*)pv8_kernel,
                            hipFuncAttributeMaxDynamicSharedMemorySize, 98816);

  cast_all_kernel<<<11264, 256, 0, stream>>>(x, Wq, Wk, Wv, xb, Wb);

  qkproj_kernel<<<dim3(32, 8), 512, 131072, stream>>>(xb, Wb, bq, bk, Qb);
  vproj_kernel<<<dim3(64, 4), 512, 98304, stream>>>(xb, Wb + 2097152, bv, Vt);

  sc8_kernel<<<dim3(8, 8, 4), 512, 131072, stream>>>(Qb, Kb, Pb, rowpart);
  pv8_kernel<<<dim3(16, 4, 4), 512, 98816, stream>>>(Pb, Vt, rowpart, out);
}